// Round 1
// baseline (349.103 us; speedup 1.0000x reference)
//
#include <hip/hip_runtime.h>

#define RM_EPS 1e-10f
#define RM_N   128          // samples per ray
#define RM_F   3            // feature channels

// 4 rays per 64-lane wave: each 16-lane group owns one ray,
// each lane handles 8 consecutive samples (lg*8 .. lg*8+7).
__global__ __launch_bounds__(256) void raymarch_kernel(
    const float* __restrict__ dens,   // (n_rays, 128)
    const float* __restrict__ feat,   // (n_rays, 128, 3)
    const float* __restrict__ len,    // (n_rays, 128)
    float* __restrict__ out,          // (n_rays, 4)
    int n_rays)
{
    const int tid  = blockIdx.x * blockDim.x + threadIdx.x;
    const int wave = tid >> 6;
    const int lane = (int)(threadIdx.x & 63);
    const int lg   = lane & 15;          // lane within the 16-lane ray group

    const int ray = wave * 4 + (lane >> 4);
    if (ray >= n_rays) return;

    const long long rbase = (long long)ray * RM_N;

    // 16B vector loads, fully coalesced (each group reads a contiguous ray)
    const float4* dp = (const float4*)(dens + rbase) + lg * 2;
    const float4* lp = (const float4*)(len  + rbase) + lg * 2;
    const float4* fp = (const float4*)(feat + rbase * RM_F) + lg * 6;

    const float4 dA = dp[0], dB = dp[1];
    const float4 lA = lp[0], lB = lp[1];
    const float4 f0 = fp[0], f1 = fp[1], f2 = fp[2];
    const float4 f3 = fp[3], f4 = fp[4], f5 = fp[5];

    const float d[8]   = {dA.x, dA.y, dA.z, dA.w, dB.x, dB.y, dB.z, dB.w};
    const float ln8[8] = {lA.x, lA.y, lA.z, lA.w, lB.x, lB.y, lB.z, lB.w};
    const float f[24]  = {f0.x, f0.y, f0.z, f0.w,  f1.x, f1.y, f1.z, f1.w,
                          f2.x, f2.y, f2.z, f2.w,  f3.x, f3.y, f3.z, f3.w,
                          f4.x, f4.y, f4.z, f4.w,  f5.x, f5.y, f5.z, f5.w};

    // Local exclusive prefix of absorption terms t_i = 1 + eps - d_i.
    // u[i] = d[i] * prod_{j<i} t_j  (weight up to the lane-global factor e)
    float u[8];
    float run = 1.0f;
    #pragma unroll
    for (int i = 0; i < 8; ++i) {
        u[i] = d[i] * run;
        run *= 1.0f + RM_EPS - d[i];
    }
    float p = run;   // product of this lane's 8 t-values

    // Per-lane partial sums — independent of the scan result, so this VALU
    // work overlaps the DS-latency chain of the scan below.
    float s0 = 0.f, s1 = 0.f, s2 = 0.f, sd = 0.f, sa = 0.f;
    #pragma unroll
    for (int i = 0; i < 8; ++i) {
        s0 += u[i] * f[i * 3 + 0];
        s1 += u[i] * f[i * 3 + 1];
        s2 += u[i] * f[i * 3 + 2];
        sd += u[i] * ln8[i];
        sa += u[i];
    }

    // Inclusive multiplicative scan of p across the 16-lane group.
    // Guarded shfl_up never consumes a cross-group value.
    #pragma unroll
    for (int off = 1; off < 16; off <<= 1) {
        float q = __shfl_up(p, off);
        p *= (lg >= off) ? q : 1.0f;
    }
    // Exclusive prefix: absorption before this lane's first sample.
    float e = __shfl_up(p, 1);
    if (lg == 0) e = 1.0f;

    s0 *= e; s1 *= e; s2 *= e; sd *= e; sa *= e;

    // Butterfly reduce within the 16-lane group (xor masks <16 never cross groups)
    #pragma unroll
    for (int off = 8; off > 0; off >>= 1) {
        s0 += __shfl_xor(s0, off);
        s1 += __shfl_xor(s1, off);
        s2 += __shfl_xor(s2, off);
        sd += __shfl_xor(sd, off);
        sa += __shfl_xor(sa, off);
    }

    // lengths[..., -1] lives in lane lg==15 of this group (lB.w)
    const float last_len = __shfl(lB.w, (lane & 48) | 15);

    if (lg == 0) {
        const float bg = 1.0f - sa;
        float4 o;
        o.x = s0 + bg;
        o.y = s1 + bg;
        o.z = s2 + bg;
        o.w = sd + bg * last_len;
        ((float4*)out)[ray] = o;   // 4 lanes/wave write 64B contiguous
    }
}

extern "C" void kernel_launch(void* const* d_in, const int* in_sizes, int n_in,
                              void* d_out, int out_size, void* d_ws, size_t ws_size,
                              hipStream_t stream) {
    const float* dens = (const float*)d_in[0];  // rays_densities (B,R,N,1)
    const float* feat = (const float*)d_in[1];  // rays_features  (B,R,N,3)
    const float* len  = (const float*)d_in[2];  // lengths        (B,R,N)
    float* out = (float*)d_out;                 // (B,R,4)

    const int n_rays = in_sizes[0] / RM_N;      // B*R = 131072
    const int rays_per_block = (256 / 64) * 4;  // 4 waves * 4 rays = 16
    const int grid = (n_rays + rays_per_block - 1) / rays_per_block;
    raymarch_kernel<<<grid, 256, 0, stream>>>(dens, feat, len, out, n_rays);
}